// Round 1
// baseline (93.431 us; speedup 1.0000x reference)
//
#include <hip/hip_runtime.h>

// Butterfly (untied, increasing stride): BATCH=16384, N=1024, M=10, NSTACK=1.
// out = butterfly_mult(twiddle, x) + bias, all float32.
//
// Layout: one wave handles RPW rows; lane holds elements pos = lane*16 + e.
// Stages 0..3: in-register pairs (bits 0..3). Stages 4..9: cross-lane via
// __shfl_xor on lane bit (s-4). Twiddle idx for stage s = pos with bit s
// deleted; twiddle[0][s][idx][i][j] is 4 contiguous floats per idx.

#define BATCH 16384
#define NCOL 1024
#define RPW 4  // rows per wave

__global__ __launch_bounds__(256) void butterfly_kernel(
    const float* __restrict__ x,
    const float* __restrict__ tw,
    const float* __restrict__ bias,
    float* __restrict__ out)
{
    const int lane = threadIdx.x & 63;
    const int wave_in_block = threadIdx.x >> 6;
    const int gwave = blockIdx.x * 4 + wave_in_block;
    const int row0 = gwave * RPW;
    if (row0 >= BATCH) return;

    float v[RPW][16];

    // ---- load x: 4 float4 per row per lane, coalesced at line granularity
    const float4* x4 = reinterpret_cast<const float4*>(x);
    #pragma unroll
    for (int q = 0; q < RPW; ++q) {
        const int base = ((row0 + q) * NCOL + lane * 16) >> 2;
        #pragma unroll
        for (int k = 0; k < 4; ++k) {
            float4 t = x4[base + k];
            v[q][k * 4 + 0] = t.x;
            v[q][k * 4 + 1] = t.y;
            v[q][k * 4 + 2] = t.z;
            v[q][k * 4 + 3] = t.w;
        }
    }

    // ---- stages 0..3: pairs within the 16 in-lane elements
    #pragma unroll
    for (int s = 0; s < 4; ++s) {
        // idx = lane*8 + j, j=0..7; twiddle[s][idx][.][.] = float4
        const float4* t4 = reinterpret_cast<const float4*>(tw + s * 2048);
        #pragma unroll
        for (int j = 0; j < 8; ++j) {
            const float4 T = t4[lane * 8 + j];
            const int e0 = ((j >> s) << (s + 1)) | (j & ((1 << s) - 1));
            const int e1 = e0 | (1 << s);
            #pragma unroll
            for (int q = 0; q < RPW; ++q) {
                const float a = v[q][e0];
                const float b = v[q][e1];
                v[q][e0] = T.x * a + T.y * b;
                v[q][e1] = T.z * a + T.w * b;
            }
        }
    }

    // ---- stages 4..9: partner lane = lane ^ (1 << (s-4))
    #pragma unroll
    for (int s = 4; s < 10; ++s) {
        const int bbit = s - 4;
        const int m = 1 << bbit;
        const int i = (lane >> bbit) & 1;                       // bit s of pos
        const int lp = ((lane >> (bbit + 1)) << bbit) | (lane & (m - 1));
        // idx = lp*16 + e; need t[idx][i][0..1] = float2 at (idx*2 + i)
        const float2* t2 = reinterpret_cast<const float2*>(tw + s * 2048);
        float2 T[16];
        #pragma unroll
        for (int e = 0; e < 16; ++e) {
            T[e] = t2[(lp * 16 + e) * 2 + i];
        }
        #pragma unroll
        for (int q = 0; q < RPW; ++q) {
            #pragma unroll
            for (int e = 0; e < 16; ++e) {
                const float own = v[q][e];
                const float p = __shfl_xor(own, m, 64);
                const float x0 = i ? p : own;   // value at bit_s = 0
                const float x1 = i ? own : p;   // value at bit_s = 1
                v[q][e] = T[e].x * x0 + T[e].y * x1;
            }
        }
    }

    // ---- bias + store
    float4* o4 = reinterpret_cast<float4*>(out);
    const float4* b4 = reinterpret_cast<const float4*>(bias);
    #pragma unroll
    for (int k = 0; k < 4; ++k) {
        const float4 bb = b4[lane * 4 + k];
        #pragma unroll
        for (int q = 0; q < RPW; ++q) {
            float4 t;
            t.x = v[q][k * 4 + 0] + bb.x;
            t.y = v[q][k * 4 + 1] + bb.y;
            t.z = v[q][k * 4 + 2] + bb.z;
            t.w = v[q][k * 4 + 3] + bb.w;
            o4[(((row0 + q) * NCOL + lane * 16) >> 2) + k] = t;
        }
    }
}

extern "C" void kernel_launch(void* const* d_in, const int* in_sizes, int n_in,
                              void* d_out, int out_size, void* d_ws, size_t ws_size,
                              hipStream_t stream) {
    const float* x    = (const float*)d_in[0];  // (16384, 1024)
    const float* tw   = (const float*)d_in[1];  // (1, 10, 512, 2, 2)
    const float* bias = (const float*)d_in[2];  // (1024,)
    float* out = (float*)d_out;

    // BATCH/RPW waves total, 4 waves (256 threads) per block
    const int total_waves = BATCH / RPW;      // 4096
    const int blocks = total_waves / 4;       // 1024
    butterfly_kernel<<<blocks, 256, 0, stream>>>(x, tw, bias, out);
}

// Round 2
// 60.247 us; speedup vs baseline: 1.5508x; 1.5508x over previous
//
#include <hip/hip_runtime.h>

// Butterfly (untied, increasing stride): BATCH=16384, N=1024, M=10, NSTACK=1.
// out = butterfly_mult(twiddle, x) + bias, all float32.
//
// Layout v2: pos = e_hi*256 + lane*4 + e_lo  (e_hi, e_lo in 0..3).
//   - global loads/stores are float4 at lane-contiguous addresses
//     (64 lanes x 16B = 1KB per instruction, full cache lines -> no
//     write amplification).
//   - stages 0..1: in-register pairs over e_lo bits.
//   - stages 2..7: cross-lane __shfl_xor over lane bits.
//   - stages 8..9: in-register pairs over e_hi bits.

#define BATCH 16384
#define NCOL 1024
#define RPW 4  // rows per wave

__global__ __launch_bounds__(256) void butterfly_kernel(
    const float* __restrict__ x,
    const float* __restrict__ tw,
    const float* __restrict__ bias,
    float* __restrict__ out)
{
    const int lane = threadIdx.x & 63;
    const int wave_in_block = threadIdx.x >> 6;
    const int gwave = blockIdx.x * 4 + wave_in_block;
    const int row0 = gwave * RPW;
    if (row0 >= BATCH) return;

    // v[q][e_hi][e_lo] = element at col e_hi*256 + lane*4 + e_lo of row row0+q
    float v[RPW][4][4];

    // ---- load x: fully coalesced float4
    const float4* x4 = reinterpret_cast<const float4*>(x);
    #pragma unroll
    for (int q = 0; q < RPW; ++q) {
        #pragma unroll
        for (int eh = 0; eh < 4; ++eh) {
            float4 t = x4[(row0 + q) * 256 + eh * 64 + lane];
            v[q][eh][0] = t.x;
            v[q][eh][1] = t.y;
            v[q][eh][2] = t.z;
            v[q][eh][3] = t.w;
        }
    }

    // ---- stage 0: pairs (e_lo 0,1) and (2,3); idx = e_hi*128 + lane*2 + j
    {
        const float4* t4 = reinterpret_cast<const float4*>(tw + 0 * 2048);
        #pragma unroll
        for (int eh = 0; eh < 4; ++eh) {
            #pragma unroll
            for (int j = 0; j < 2; ++j) {
                const float4 T = t4[eh * 128 + lane * 2 + j];
                #pragma unroll
                for (int q = 0; q < RPW; ++q) {
                    const float a = v[q][eh][2 * j];
                    const float b = v[q][eh][2 * j + 1];
                    v[q][eh][2 * j]     = T.x * a + T.y * b;
                    v[q][eh][2 * j + 1] = T.z * a + T.w * b;
                }
            }
        }
    }

    // ---- stage 1: pairs (e_lo 0,2) and (1,3); idx = e_hi*128 + lane*2 + j
    {
        const float4* t4 = reinterpret_cast<const float4*>(tw + 1 * 2048);
        #pragma unroll
        for (int eh = 0; eh < 4; ++eh) {
            #pragma unroll
            for (int j = 0; j < 2; ++j) {
                const float4 T = t4[eh * 128 + lane * 2 + j];
                #pragma unroll
                for (int q = 0; q < RPW; ++q) {
                    const float a = v[q][eh][j];
                    const float b = v[q][eh][j + 2];
                    v[q][eh][j]     = T.x * a + T.y * b;
                    v[q][eh][j + 2] = T.z * a + T.w * b;
                }
            }
        }
    }

    // ---- stages 2..7: partner lane = lane ^ (1 << (s-2))
    #pragma unroll
    for (int s = 2; s < 8; ++s) {
        const int bbit = s - 2;
        const int m = 1 << bbit;
        const int i = (lane >> bbit) & 1;   // bit s of pos
        const int lp = ((lane >> (bbit + 1)) << bbit) | (lane & (m - 1));
        // idx = e_hi*128 + lp*4 + e_lo ; twiddle element float2 at idx*2 + i
        const float2* t2 = reinterpret_cast<const float2*>(tw + s * 2048);
        float2 T[4][4];
        #pragma unroll
        for (int eh = 0; eh < 4; ++eh) {
            #pragma unroll
            for (int el = 0; el < 4; ++el) {
                T[eh][el] = t2[(eh * 128 + lp * 4 + el) * 2 + i];
            }
        }
        #pragma unroll
        for (int q = 0; q < RPW; ++q) {
            #pragma unroll
            for (int eh = 0; eh < 4; ++eh) {
                #pragma unroll
                for (int el = 0; el < 4; ++el) {
                    const float own = v[q][eh][el];
                    const float p = __shfl_xor(own, m, 64);
                    const float x0 = i ? p : own;   // value at bit_s = 0
                    const float x1 = i ? own : p;   // value at bit_s = 1
                    v[q][eh][el] = T[eh][el].x * x0 + T[eh][el].y * x1;
                }
            }
        }
    }

    // ---- stage 8: pairs (e_hi 0,1),(2,3); idx = g*256 + lane*4 + e_lo
    {
        const float4* t4 = reinterpret_cast<const float4*>(tw + 8 * 2048);
        #pragma unroll
        for (int g = 0; g < 2; ++g) {
            #pragma unroll
            for (int el = 0; el < 4; ++el) {
                const float4 T = t4[g * 256 + lane * 4 + el];
                #pragma unroll
                for (int q = 0; q < RPW; ++q) {
                    const float a = v[q][2 * g][el];
                    const float b = v[q][2 * g + 1][el];
                    v[q][2 * g][el]     = T.x * a + T.y * b;
                    v[q][2 * g + 1][el] = T.z * a + T.w * b;
                }
            }
        }
    }

    // ---- stage 9: pairs (e_hi 0,2),(1,3); idx = h*256 + lane*4 + e_lo
    {
        const float4* t4 = reinterpret_cast<const float4*>(tw + 9 * 2048);
        #pragma unroll
        for (int h = 0; h < 2; ++h) {
            #pragma unroll
            for (int el = 0; el < 4; ++el) {
                const float4 T = t4[h * 256 + lane * 4 + el];
                #pragma unroll
                for (int q = 0; q < RPW; ++q) {
                    const float a = v[q][h][el];
                    const float b = v[q][h + 2][el];
                    v[q][h][el]     = T.x * a + T.y * b;
                    v[q][h + 2][el] = T.z * a + T.w * b;
                }
            }
        }
    }

    // ---- bias + store: fully coalesced float4
    float4* o4 = reinterpret_cast<float4*>(out);
    const float4* b4 = reinterpret_cast<const float4*>(bias);
    #pragma unroll
    for (int eh = 0; eh < 4; ++eh) {
        const float4 bb = b4[eh * 64 + lane];
        #pragma unroll
        for (int q = 0; q < RPW; ++q) {
            float4 t;
            t.x = v[q][eh][0] + bb.x;
            t.y = v[q][eh][1] + bb.y;
            t.z = v[q][eh][2] + bb.z;
            t.w = v[q][eh][3] + bb.w;
            o4[(row0 + q) * 256 + eh * 64 + lane] = t;
        }
    }
}

extern "C" void kernel_launch(void* const* d_in, const int* in_sizes, int n_in,
                              void* d_out, int out_size, void* d_ws, size_t ws_size,
                              hipStream_t stream) {
    const float* x    = (const float*)d_in[0];  // (16384, 1024)
    const float* tw   = (const float*)d_in[1];  // (1, 10, 512, 2, 2)
    const float* bias = (const float*)d_in[2];  // (1024,)
    float* out = (float*)d_out;

    const int total_waves = BATCH / RPW;      // 4096
    const int blocks = total_waves / 4;       // 1024
    butterfly_kernel<<<blocks, 256, 0, stream>>>(x, tw, bias, out);
}